// Round 2
// baseline (791.464 us; speedup 1.0000x reference)
//
#include <hip/hip_runtime.h>
#include <stdint.h>

#define NNODES 50000
#define NEDGES 1600000
#define HID 512
#define MPAD 50048   // 391*128
#define NEG_SLOPE 0.01f
#define NPB 16       // nodes per block in meanyz

typedef __attribute__((ext_vector_type(8))) short bf16x8;
typedef __attribute__((ext_vector_type(8))) unsigned short u16x8;
typedef __attribute__((ext_vector_type(4))) float f32x4;

__device__ __forceinline__ float bf2f(unsigned short u) {
  unsigned int x = ((unsigned int)u) << 16;
  return __builtin_bit_cast(float, x);
}
__device__ __forceinline__ unsigned short f2bf(float f) {
  unsigned int u = __builtin_bit_cast(unsigned int, f);
  u += 0x7FFFu + ((u >> 16) & 1u);
  return (unsigned short)(u >> 16);
}
__device__ __forceinline__ void gload_lds16(const void* g, void* l) {
  __builtin_amdgcn_global_load_lds(
      (const __attribute__((address_space(1))) void*)g,
      (__attribute__((address_space(3))) void*)l, 16, 0, 0);
}

// ---- zero counts + detect edge_index storage (int32 vs int64) ----
// int64 layout: u32 at odd positions are high words == 0 (values in [0,50000)).
// int32 layout: odd positions are src values, ~surely some nonzero.
__global__ void init_misc(const int* __restrict__ ei, int* __restrict__ flag,
                          int* __restrict__ cnt) {
  int i = blockIdx.x * 256 + threadIdx.x;
  if (i < NNODES) cnt[i] = 0;
  if (blockIdx.x == 0) {
    if (threadIdx.x == 0) *flag = 0;
    __syncthreads();
    if (threadIdx.x < 64) {
      if (ei[2 * threadIdx.x + 1] != 0) atomicOr(flag, 1);
    }
  }
}

__global__ void count_edges(const int* __restrict__ ei, const int* __restrict__ flag,
                            int* __restrict__ cnt) {
  int e = blockIdx.x * 256 + threadIdx.x;
  if (e >= NEDGES) return;
  int f = *flag;
  int d = f ? ei[(size_t)NEDGES + e] : ei[2 * ((size_t)NEDGES + e)];
  if ((unsigned)d < NNODES) atomicAdd(&cnt[d], 1);
}

__global__ __launch_bounds__(1024) void scan_counts(const int* __restrict__ cnt,
                                                    int* __restrict__ rp,
                                                    int* __restrict__ next) {
  __shared__ int s[1024];
  int t = threadIdx.x;
  int base = t * 49;
  int sum = 0;
  for (int i = 0; i < 49; i++) {
    int idx = base + i;
    if (idx < NNODES) sum += cnt[idx];
  }
  s[t] = sum;
  __syncthreads();
  for (int off = 1; off < 1024; off <<= 1) {
    int v = (t >= off) ? s[t - off] : 0;
    __syncthreads();
    s[t] += v;
    __syncthreads();
  }
  int pre = (t > 0) ? s[t - 1] : 0;
  for (int i = 0; i < 49; i++) {
    int idx = base + i;
    if (idx < NNODES) { rp[idx] = pre; next[idx] = pre; pre += cnt[idx]; }
  }
  if (t == 1023) rp[NNODES] = s[1023];
}

__global__ void scatter_edges(const int* __restrict__ ei, const int* __restrict__ flag,
                              int* __restrict__ next, int* __restrict__ colx) {
  int e = blockIdx.x * 256 + threadIdx.x;
  if (e >= NEDGES) return;
  int f = *flag;
  int sN = f ? ei[e] : ei[2 * (size_t)e];
  int d  = f ? ei[(size_t)NEDGES + e] : ei[2 * ((size_t)NEDGES + e)];
  if ((unsigned)d >= NNODES) return;
  if ((unsigned)sN >= NNODES) sN = 0;
  int pos = atomicAdd(&next[d], 1);
  colx[pos] = sN;
}

// ---- Wt0[n][k] = bf16(W_in[k][n]) ----
__global__ void tcast(const float* __restrict__ w, unsigned short* __restrict__ wt) {
  int i = blockIdx.x * 256 + threadIdx.x;  // 262144
  int n = i >> 9, k = i & 511;
  wt[i] = f2bf(w[(k << 9) | n]);
}

// ---- Wlp = W2_l@W_out, Wrp = W2_r@W_out, bp = b2_l@W_out + b_out ----
__global__ void small_w(const float* __restrict__ W2l, const float* __restrict__ W2r,
                        const float* __restrict__ Wout, const float* __restrict__ b2l,
                        const float* __restrict__ bout,
                        float* __restrict__ Wlp, float* __restrict__ Wrp,
                        float* __restrict__ bp) {
  int gid = blockIdx.x * 256 + threadIdx.x;
  if (gid < 2048) {
    int k = gid >> 2, j = gid & 3;
    float s = 0.f;
    for (int i = 0; i < 512; i++) s += W2l[k * 512 + i] * Wout[i * 4 + j];
    Wlp[gid] = s;
  } else if (gid < 4096) {
    int g = gid - 2048;
    int k = g >> 2, j = g & 3;
    float s = 0.f;
    for (int i = 0; i < 512; i++) s += W2r[k * 512 + i] * Wout[i * 4 + j];
    Wrp[g] = s;
  } else if (gid < 4100) {
    int j = gid - 4096;
    float s = 0.f;
    for (int i = 0; i < 512; i++) s += b2l[i] * Wout[i * 4 + j];
    bp[j] = s + bout[j];
  }
}

// ---- P1=W1_l@Wlp, Q1=W1_r@Wlp, P2=W1_l@Wrp, Q2=W1_r@Wrp, cyz=b1_l@{Wlp,Wrp} ----
__global__ void small_w2(const float* __restrict__ W1l, const float* __restrict__ W1r,
                         const float* __restrict__ b1l,
                         const float* __restrict__ Wlp, const float* __restrict__ Wrp,
                         float* __restrict__ P1, float* __restrict__ Q1,
                         float* __restrict__ P2, float* __restrict__ Q2,
                         float* __restrict__ cyz) {
  int gid = blockIdx.x * 256 + threadIdx.x;
  if (gid < 8192) {
    int sel = gid >> 11;
    int g = gid & 2047;
    int k = g >> 2, j = g & 3;
    const float* A = (sel == 0 || sel == 2) ? W1l : W1r;
    const float* B = (sel < 2) ? Wlp : Wrp;
    float s = 0.f;
    for (int i = 0; i < 512; i++) s += A[k * 512 + i] * B[i * 4 + j];
    float* C = (sel == 0) ? P1 : (sel == 1) ? Q1 : (sel == 2) ? P2 : Q2;
    C[g] = s;
  } else if (gid < 8200) {
    int j = gid - 8192;   // 0..3 -> cy, 4..7 -> cz
    const float* B = (j < 4) ? Wlp : Wrp;
    int jj = j & 3;
    float s = 0.f;
    for (int i = 0; i < 512; i++) s += b1l[i] * B[i * 4 + jj];
    cyz[j] = s;
  }
}

// ---- GEMM1: x0 = leaky(feat(fp32) @ W_in + b_in) -> bf16 [MPAD][512] ----
// A fp32 reg-staged+cast to LDS; B (pre-transposed bf16) via global_load_lds.
__global__ __launch_bounds__(256) void gemm1(
    const float* __restrict__ A, const unsigned short* __restrict__ Bt,
    const float* __restrict__ bias, unsigned short* __restrict__ C) {
  __shared__ unsigned short As[128 * 32];
  __shared__ unsigned short Bs[128 * 32];
  const int tid = threadIdx.x;
  const int wave = tid >> 6, lane = tid & 63;
  const int bid = blockIdx.x;
  const int bm = (bid >> 2) * 128, bn = (bid & 3) * 128;
  const int wr = wave >> 1, wc = wave & 1;
  const int r15 = lane & 15, kl = lane >> 4;
  const int srow = lane >> 2, soff = (lane & 3) * 8;

  f32x4 acc[4][4];
#pragma unroll
  for (int i = 0; i < 4; i++)
#pragma unroll
    for (int j = 0; j < 4; j++) acc[i][j] = {0.f, 0.f, 0.f, 0.f};

  for (int kt = 0; kt < HID / 32; ++kt) {
    // B: async global->LDS (wave-uniform LDS base + lane*16B)
#pragma unroll
    for (int rr = 0; rr < 2; ++rr) {
      int c = wave * 2 + rr;
      int row = c * 16 + srow;
      gload_lds16(Bt + (size_t)(bn + row) * HID + kt * 32 + soff, (void*)&Bs[c * 512]);
    }
    // A: fp32 load -> bf16 pack -> ds_write (2 slots of 8 elems per thread)
#pragma unroll
    for (int ss = 0; ss < 2; ++ss) {
      int s = tid + ss * 256;
      int row = s >> 2, k8 = (s & 3) * 8;
      int garow = bm + row;
      if (garow >= NNODES) garow = 0;  // pad rows: values unused
      const float* ga = A + (size_t)garow * HID + kt * 32 + k8;
      float4 v0 = *reinterpret_cast<const float4*>(ga);
      float4 v1 = *reinterpret_cast<const float4*>(ga + 4);
      u16x8 pk;
      pk[0] = f2bf(v0.x); pk[1] = f2bf(v0.y); pk[2] = f2bf(v0.z); pk[3] = f2bf(v0.w);
      pk[4] = f2bf(v1.x); pk[5] = f2bf(v1.y); pk[6] = f2bf(v1.z); pk[7] = f2bf(v1.w);
      *reinterpret_cast<u16x8*>(&As[row * 32 + k8]) = pk;
    }
    __syncthreads();
    bf16x8 af[4], bfr[4];
#pragma unroll
    for (int mi = 0; mi < 4; ++mi)
      af[mi] = *reinterpret_cast<const bf16x8*>(&As[(wr * 64 + mi * 16 + r15) * 32 + kl * 8]);
#pragma unroll
    for (int ni = 0; ni < 4; ++ni)
      bfr[ni] = *reinterpret_cast<const bf16x8*>(&Bs[(wc * 64 + ni * 16 + r15) * 32 + kl * 8]);
#pragma unroll
    for (int mi = 0; mi < 4; ++mi)
#pragma unroll
      for (int ni = 0; ni < 4; ++ni)
        acc[mi][ni] = __builtin_amdgcn_mfma_f32_16x16x32_bf16(af[mi], bfr[ni], acc[mi][ni], 0, 0, 0);
    __syncthreads();
  }
  // epilogue: D layout col=lane&15, row=(lane>>4)*4+reg  [m89-verified]
#pragma unroll
  for (int ni = 0; ni < 4; ++ni) {
    int col = bn + wc * 64 + ni * 16 + r15;
    float bv = bias[col];
#pragma unroll
    for (int mi = 0; mi < 4; ++mi) {
#pragma unroll
      for (int rg = 0; rg < 4; ++rg) {
        int row = bm + wr * 64 + mi * 16 + kl * 4 + rg;
        float v = acc[mi][ni][rg] + bv;
        v = (v >= 0.f) ? v : NEG_SLOPE * v;
        if (row < NNODES) C[(size_t)row * HID + col] = f2bf(v);
      }
    }
  }
}

// ---- fused mean-aggregate + y/z projection ----
// y[n][j] = sum_k mean1[n][k]*P1[k][j] + x0[n][k]*Q1[k][j] + cy[j]
// z[n][j] = sum_k mean1[n][k]*P2[k][j] + x0[n][k]*Q2[k][j] + cz[j]
__global__ __launch_bounds__(128) void meanyz(
    const unsigned short* __restrict__ x0h, const int* __restrict__ rp,
    const int* __restrict__ colx,
    const float* __restrict__ P1, const float* __restrict__ Q1,
    const float* __restrict__ P2, const float* __restrict__ Q2,
    const float* __restrict__ cyz,
    float* __restrict__ y, float* __restrict__ z) {
  const int t = threadIdx.x;
  const int n0 = blockIdx.x * NPB;
  float4 p1[4], q1[4], p2[4], q2[4];
#pragma unroll
  for (int i = 0; i < 4; i++) {
    int k = t * 4 + i;
    p1[i] = *reinterpret_cast<const float4*>(P1 + k * 4);
    q1[i] = *reinterpret_cast<const float4*>(Q1 + k * 4);
    p2[i] = *reinterpret_cast<const float4*>(P2 + k * 4);
    q2[i] = *reinterpret_cast<const float4*>(Q2 + k * 4);
  }
  __shared__ float red[2][8];
  for (int nn = 0; nn < NPB; ++nn) {
    int n = n0 + nn;
    int e0 = rp[n], e1 = rp[n + 1];
    float a0[4] = {0.f, 0.f, 0.f, 0.f};
    float a1[4] = {0.f, 0.f, 0.f, 0.f};
    int e = e0;
    for (; e + 1 < e1; e += 2) {
      int s0 = colx[e], s1 = colx[e + 1];
      ushort4 v0 = *reinterpret_cast<const ushort4*>(x0h + (size_t)s0 * HID + t * 4);
      ushort4 v1 = *reinterpret_cast<const ushort4*>(x0h + (size_t)s1 * HID + t * 4);
      a0[0] += bf2f(v0.x); a0[1] += bf2f(v0.y); a0[2] += bf2f(v0.z); a0[3] += bf2f(v0.w);
      a1[0] += bf2f(v1.x); a1[1] += bf2f(v1.y); a1[2] += bf2f(v1.z); a1[3] += bf2f(v1.w);
    }
    if (e < e1) {
      int s0 = colx[e];
      ushort4 v0 = *reinterpret_cast<const ushort4*>(x0h + (size_t)s0 * HID + t * 4);
      a0[0] += bf2f(v0.x); a0[1] += bf2f(v0.y); a0[2] += bf2f(v0.z); a0[3] += bf2f(v0.w);
    }
    float sc = (e1 > e0) ? 1.f / (float)(e1 - e0) : 0.f;
    ushort4 sv = *reinterpret_cast<const ushort4*>(x0h + (size_t)n * HID + t * 4);
    float sf[4] = {bf2f(sv.x), bf2f(sv.y), bf2f(sv.z), bf2f(sv.w)};
    float py[4] = {0.f, 0.f, 0.f, 0.f};
    float pz[4] = {0.f, 0.f, 0.f, 0.f};
#pragma unroll
    for (int i = 0; i < 4; i++) {
      float m = (a0[i] + a1[i]) * sc;
      float x = sf[i];
      py[0] += m * p1[i].x + x * q1[i].x;
      py[1] += m * p1[i].y + x * q1[i].y;
      py[2] += m * p1[i].z + x * q1[i].z;
      py[3] += m * p1[i].w + x * q1[i].w;
      pz[0] += m * p2[i].x + x * q2[i].x;
      pz[1] += m * p2[i].y + x * q2[i].y;
      pz[2] += m * p2[i].z + x * q2[i].z;
      pz[3] += m * p2[i].w + x * q2[i].w;
    }
#pragma unroll
    for (int off = 32; off > 0; off >>= 1) {
#pragma unroll
      for (int j = 0; j < 4; j++) {
        py[j] += __shfl_xor(py[j], off);
        pz[j] += __shfl_xor(pz[j], off);
      }
    }
    int wv = t >> 6, ln = t & 63;
    if (ln == 0) {
#pragma unroll
      for (int j = 0; j < 4; j++) { red[wv][j] = py[j]; red[wv][4 + j] = pz[j]; }
    }
    __syncthreads();
    if (t < 4) y[(size_t)n * 4 + t] = red[0][t] + red[1][t] + cyz[t];
    else if (t < 8) z[(size_t)n * 4 + (t - 4)] = red[0][t] + red[1][t] + cyz[t];
    __syncthreads();
  }
}

// ---- out[n][j] = mean_{src in N(n)} y[src][j] + z[n][j] + bp[j] ----
__global__ __launch_bounds__(256) void finalize(
    const int* __restrict__ rp, const int* __restrict__ colx,
    const float* __restrict__ y, const float* __restrict__ z,
    const float* __restrict__ bp, float* __restrict__ out) {
  int wv = threadIdx.x >> 6, l = threadIdx.x & 63;
  int n = blockIdx.x * 4 + wv;
  if (n >= NNODES) return;
  int e0 = rp[n], e1 = rp[n + 1];
  int j = l & 3, g = l >> 2;
  float acc = 0.f;
  for (int e = e0 + g; e < e1; e += 16) {
    int s = colx[e];
    acc += y[(size_t)s * 4 + j];
  }
  acc += __shfl_xor(acc, 4);
  acc += __shfl_xor(acc, 8);
  acc += __shfl_xor(acc, 16);
  acc += __shfl_xor(acc, 32);
  if (l < 4) {
    float sc = (e1 > e0) ? 1.f / (float)(e1 - e0) : 0.f;
    out[(size_t)n * 4 + l] = acc * sc + z[(size_t)n * 4 + l] + bp[l];
  }
}

extern "C" void kernel_launch(void* const* d_in, const int* in_sizes, int n_in,
                              void* d_out, int out_size, void* d_ws, size_t ws_size,
                              hipStream_t stream) {
  const float* feat = (const float*)d_in[0];
  const int* ei = (const int*)d_in[1];
  const float* W_in = (const float*)d_in[3];
  const float* b_in = (const float*)d_in[4];
  const float* W1l = (const float*)d_in[5];
  const float* b1l = (const float*)d_in[6];
  const float* W1r = (const float*)d_in[7];
  const float* W2l = (const float*)d_in[8];
  const float* b2l = (const float*)d_in[9];
  const float* W2r = (const float*)d_in[10];
  const float* Wout = (const float*)d_in[11];
  const float* bout = (const float*)d_in[12];
  float* out = (float*)d_out;

  // ---- workspace layout (all 16B aligned), total ~60.4 MB ----
  char* ws = (char*)d_ws;
  size_t off = 0;
  auto alloc = [&](size_t bytes) {
    void* p = ws + off;
    off += (bytes + 15) & ~(size_t)15;
    return p;
  };
  int* flag = (int*)alloc(16);
  int* cnt  = (int*)alloc(NNODES * 4);
  int* next = (int*)alloc(NNODES * 4);
  int* rp   = (int*)alloc((NNODES + 1) * 4);
  int* colx = (int*)alloc((size_t)NEDGES * 4);
  unsigned short* Wt0 = (unsigned short*)alloc(512 * 512 * 2);
  float* Wlp = (float*)alloc(2048 * 4);
  float* Wrp = (float*)alloc(2048 * 4);
  float* bp  = (float*)alloc(16);
  float* P1  = (float*)alloc(2048 * 4);
  float* Q1  = (float*)alloc(2048 * 4);
  float* P2  = (float*)alloc(2048 * 4);
  float* Q2  = (float*)alloc(2048 * 4);
  float* cyz = (float*)alloc(32);
  float* yv  = (float*)alloc((size_t)NNODES * 4 * 4);
  float* zv  = (float*)alloc((size_t)NNODES * 4 * 4);
  unsigned short* x0h = (unsigned short*)alloc((size_t)MPAD * HID * 2);
  (void)ws_size;

  // CSR build (dtype-adaptive, bounds-clamped)
  init_misc<<<(NNODES + 255) / 256, 256, 0, stream>>>(ei, flag, cnt);
  count_edges<<<(NEDGES + 255) / 256, 256, 0, stream>>>(ei, flag, cnt);
  scan_counts<<<1, 1024, 0, stream>>>(cnt, rp, next);
  scatter_edges<<<(NEDGES + 255) / 256, 256, 0, stream>>>(ei, flag, next, colx);

  // weight prep
  tcast<<<1024, 256, 0, stream>>>(W_in, Wt0);
  small_w<<<17, 256, 0, stream>>>(W2l, W2r, Wout, b2l, bout, Wlp, Wrp, bp);
  small_w2<<<33, 256, 0, stream>>>(W1l, W1r, b1l, Wlp, Wrp, P1, Q1, P2, Q2, cyz);

  // pipeline
  gemm1<<<(MPAD / 128) * 4, 256, 0, stream>>>(feat, Wt0, b_in, x0h);
  meanyz<<<NNODES / NPB, 128, 0, stream>>>(x0h, rp, colx, P1, Q1, P2, Q2, cyz, yv, zv);
  finalize<<<(NNODES + 3) / 4, 256, 0, stream>>>(rp, colx, yv, zv, bp, out);
}

// Round 3
// 418.367 us; speedup vs baseline: 1.8918x; 1.8918x over previous
//
#include <hip/hip_runtime.h>
#include <stdint.h>

#define NNODES 50000
#define NEDGES 1600000
#define HID 512
#define MPAD 50048   // 391*128
#define NEG_SLOPE 0.01f
#define SCAN_BLOCKS 196  // ceil(50000/256)

typedef __attribute__((ext_vector_type(8))) short bf16x8;
typedef __attribute__((ext_vector_type(8))) unsigned short u16x8;
typedef __attribute__((ext_vector_type(4))) float f32x4;

__device__ __forceinline__ float bf2f(unsigned short u) {
  unsigned int x = ((unsigned int)u) << 16;
  return __builtin_bit_cast(float, x);
}
__device__ __forceinline__ unsigned short f2bf(float f) {
  unsigned int u = __builtin_bit_cast(unsigned int, f);
  u += 0x7FFFu + ((u >> 16) & 1u);
  return (unsigned short)(u >> 16);
}
__device__ __forceinline__ void gload_lds16(const void* g, void* l) {
  __builtin_amdgcn_global_load_lds(
      (const __attribute__((address_space(1))) void*)g,
      (__attribute__((address_space(3))) void*)l, 16, 0, 0);
}

// ---- zero counts + detect edge_index storage (int32 vs int64) ----
__global__ void init_misc(const int* __restrict__ ei, int* __restrict__ flag,
                          int* __restrict__ cnt) {
  int i = blockIdx.x * 256 + threadIdx.x;
  if (i < NNODES) cnt[i] = 0;
  if (blockIdx.x == 0) {
    if (threadIdx.x == 0) *flag = 0;
    __syncthreads();
    if (threadIdx.x < 64) {
      if (ei[2 * threadIdx.x + 1] != 0) atomicOr(flag, 1);
    }
  }
}

__global__ void count_edges(const int* __restrict__ ei, const int* __restrict__ flag,
                            int* __restrict__ cnt) {
  int e = blockIdx.x * 256 + threadIdx.x;
  if (e >= NEDGES) return;
  int f = *flag;
  int d = f ? ei[(size_t)NEDGES + e] : ei[2 * ((size_t)NEDGES + e)];
  if ((unsigned)d < NNODES) atomicAdd(&cnt[d], 1);
}

// ---- 3-phase parallel exclusive scan of cnt -> rp, next ----
__global__ __launch_bounds__(256) void scan_a(const int* __restrict__ cnt,
                                              int* __restrict__ bsum) {
  __shared__ int s[256];
  int t = threadIdx.x, i = blockIdx.x * 256 + t;
  s[t] = (i < NNODES) ? cnt[i] : 0;
  __syncthreads();
  for (int off = 128; off > 0; off >>= 1) {
    if (t < off) s[t] += s[t + off];
    __syncthreads();
  }
  if (t == 0) bsum[blockIdx.x] = s[0];
}

__global__ __launch_bounds__(256) void scan_b(const int* __restrict__ bsum,
                                              int* __restrict__ boff,
                                              int* __restrict__ rp) {
  __shared__ int s[256];
  int t = threadIdx.x;
  int v = (t < SCAN_BLOCKS) ? bsum[t] : 0;
  s[t] = v;
  __syncthreads();
  for (int off = 1; off < 256; off <<= 1) {
    int u = (t >= off) ? s[t - off] : 0;
    __syncthreads();
    s[t] += u;
    __syncthreads();
  }
  if (t < SCAN_BLOCKS) boff[t] = s[t] - v;     // exclusive
  if (t == SCAN_BLOCKS - 1) rp[NNODES] = s[t]; // total edges kept
}

__global__ __launch_bounds__(256) void scan_c(const int* __restrict__ cnt,
                                              const int* __restrict__ boff,
                                              int* __restrict__ rp,
                                              int* __restrict__ next) {
  __shared__ int s[256];
  int t = threadIdx.x, i = blockIdx.x * 256 + t;
  int v = (i < NNODES) ? cnt[i] : 0;
  s[t] = v;
  __syncthreads();
  for (int off = 1; off < 256; off <<= 1) {
    int u = (t >= off) ? s[t - off] : 0;
    __syncthreads();
    s[t] += u;
    __syncthreads();
  }
  if (i < NNODES) {
    int e = boff[blockIdx.x] + s[t] - v;
    rp[i] = e;
    next[i] = e;
  }
}

__global__ void scatter_edges(const int* __restrict__ ei, const int* __restrict__ flag,
                              int* __restrict__ next, int* __restrict__ colx) {
  int e = blockIdx.x * 256 + threadIdx.x;
  if (e >= NEDGES) return;
  int f = *flag;
  int sN = f ? ei[e] : ei[2 * (size_t)e];
  int d  = f ? ei[(size_t)NEDGES + e] : ei[2 * ((size_t)NEDGES + e)];
  if ((unsigned)d >= NNODES) return;
  if ((unsigned)sN >= NNODES) sN = 0;
  int pos = atomicAdd(&next[d], 1);
  colx[pos] = sN;
}

// ---- Wt0[n][k] = bf16(W_in[k][n]) ----
__global__ void tcast(const float* __restrict__ w, unsigned short* __restrict__ wt) {
  int i = blockIdx.x * 256 + threadIdx.x;  // 262144
  int n = i >> 9, k = i & 511;
  wt[i] = f2bf(w[(k << 9) | n]);
}

// ---- wave-parallel 512-dot: A row (contig) . B col j of [512][4] ----
__device__ __forceinline__ float wave_dot(const float* __restrict__ Arow,
                                          const float* __restrict__ B, int j) {
  int l = threadIdx.x & 63;
  float4 a0 = *reinterpret_cast<const float4*>(Arow + l * 8);
  float4 a1 = *reinterpret_cast<const float4*>(Arow + l * 8 + 4);
  const float* bb = B + (size_t)(l * 8) * 4 + j;
  float s = a0.x * bb[0] + a0.y * bb[4] + a0.z * bb[8] + a0.w * bb[12] +
            a1.x * bb[16] + a1.y * bb[20] + a1.z * bb[24] + a1.w * bb[28];
#pragma unroll
  for (int off = 1; off < 64; off <<= 1) s += __shfl_xor(s, off);
  return s;
}

// ---- smallA: Wlp = W2l@Wout, Wrp = W2r@Wout, bp = b2l@Wout + bout ----
__global__ __launch_bounds__(256) void smallA(
    const float* __restrict__ W2l, const float* __restrict__ W2r,
    const float* __restrict__ Wout, const float* __restrict__ b2l,
    const float* __restrict__ bout,
    float* __restrict__ Wlp, float* __restrict__ Wrp, float* __restrict__ bp) {
  int gw = blockIdx.x * 4 + (threadIdx.x >> 6);
  int l = threadIdx.x & 63;
  if (gw < 2048) {
    float v = wave_dot(W2l + (size_t)(gw >> 2) * 512, Wout, gw & 3);
    if (l == 0) Wlp[gw] = v;
  } else if (gw < 4096) {
    int g = gw - 2048;
    float v = wave_dot(W2r + (size_t)(g >> 2) * 512, Wout, g & 3);
    if (l == 0) Wrp[g] = v;
  } else if (gw < 4100) {
    int j = gw - 4096;
    float v = wave_dot(b2l, Wout, j);
    if (l == 0) bp[j] = v + bout[j];
  }
}

// ---- smallB: Pall[k][0:4]=W1l@Wlp, [4:8]=W1r@Wlp+W1l@Wrp, [8:12]=W1r@Wrp;
//              kb = b1l@Wlp; kc = b1l@Wrp + bp ----
__global__ __launch_bounds__(256) void smallB(
    const float* __restrict__ W1l, const float* __restrict__ W1r,
    const float* __restrict__ b1l,
    const float* __restrict__ Wlp, const float* __restrict__ Wrp,
    const float* __restrict__ bp,
    float* __restrict__ Pall, float* __restrict__ kb, float* __restrict__ kc) {
  int gw = blockIdx.x * 4 + (threadIdx.x >> 6);
  int l = threadIdx.x & 63;
  if (gw < 6144) {
    int k = gw / 12, jg = gw % 12;
    int g = jg >> 2, j = jg & 3;
    float v;
    if (g == 0) v = wave_dot(W1l + (size_t)k * 512, Wlp, j);
    else if (g == 1) v = wave_dot(W1r + (size_t)k * 512, Wlp, j) +
                         wave_dot(W1l + (size_t)k * 512, Wrp, j);
    else v = wave_dot(W1r + (size_t)k * 512, Wrp, j);
    if (l == 0) Pall[k * 12 + jg] = v;
  } else if (gw < 6152) {
    int i = gw - 6144, j = i & 3;
    if (i < 4) {
      float v = wave_dot(b1l, Wlp, j);
      if (l == 0) kb[j] = v;
    } else {
      float v = wave_dot(b1l, Wrp, j);
      if (l == 0) kc[j] = v + bp[j];
    }
  }
}

// ---- GEMM1: x0 = leaky(feat(fp32) @ W_in + b_in) -> bf16 [MPAD][512] ----
__global__ __launch_bounds__(256) void gemm1(
    const float* __restrict__ A, const unsigned short* __restrict__ Bt,
    const float* __restrict__ bias, unsigned short* __restrict__ C) {
  __shared__ unsigned short As[128 * 32];
  __shared__ unsigned short Bs[128 * 32];
  const int tid = threadIdx.x;
  const int wave = tid >> 6, lane = tid & 63;
  const int bid = blockIdx.x;
  const int bm = (bid >> 2) * 128, bn = (bid & 3) * 128;
  const int wr = wave >> 1, wc = wave & 1;
  const int r15 = lane & 15, kl = lane >> 4;
  const int srow = lane >> 2, soff = (lane & 3) * 8;

  f32x4 acc[4][4];
#pragma unroll
  for (int i = 0; i < 4; i++)
#pragma unroll
    for (int j = 0; j < 4; j++) acc[i][j] = {0.f, 0.f, 0.f, 0.f};

  for (int kt = 0; kt < HID / 32; ++kt) {
#pragma unroll
    for (int rr = 0; rr < 2; ++rr) {
      int c = wave * 2 + rr;
      int row = c * 16 + srow;
      gload_lds16(Bt + (size_t)(bn + row) * HID + kt * 32 + soff, (void*)&Bs[c * 512]);
    }
#pragma unroll
    for (int ss = 0; ss < 2; ++ss) {
      int s = tid + ss * 256;
      int row = s >> 2, k8 = (s & 3) * 8;
      int garow = bm + row;
      if (garow >= NNODES) garow = 0;
      const float* ga = A + (size_t)garow * HID + kt * 32 + k8;
      float4 v0 = *reinterpret_cast<const float4*>(ga);
      float4 v1 = *reinterpret_cast<const float4*>(ga + 4);
      u16x8 pk;
      pk[0] = f2bf(v0.x); pk[1] = f2bf(v0.y); pk[2] = f2bf(v0.z); pk[3] = f2bf(v0.w);
      pk[4] = f2bf(v1.x); pk[5] = f2bf(v1.y); pk[6] = f2bf(v1.z); pk[7] = f2bf(v1.w);
      *reinterpret_cast<u16x8*>(&As[row * 32 + k8]) = pk;
    }
    __syncthreads();
    bf16x8 af[4], bfr[4];
#pragma unroll
    for (int mi = 0; mi < 4; ++mi)
      af[mi] = *reinterpret_cast<const bf16x8*>(&As[(wr * 64 + mi * 16 + r15) * 32 + kl * 8]);
#pragma unroll
    for (int ni = 0; ni < 4; ++ni)
      bfr[ni] = *reinterpret_cast<const bf16x8*>(&Bs[(wc * 64 + ni * 16 + r15) * 32 + kl * 8]);
#pragma unroll
    for (int mi = 0; mi < 4; ++mi)
#pragma unroll
      for (int ni = 0; ni < 4; ++ni)
        acc[mi][ni] = __builtin_amdgcn_mfma_f32_16x16x32_bf16(af[mi], bfr[ni], acc[mi][ni], 0, 0, 0);
    __syncthreads();
  }
#pragma unroll
  for (int ni = 0; ni < 4; ++ni) {
    int col = bn + wc * 64 + ni * 16 + r15;
    float bv = bias[col];
#pragma unroll
    for (int mi = 0; mi < 4; ++mi) {
#pragma unroll
      for (int rg = 0; rg < 4; ++rg) {
        int row = bm + wr * 64 + mi * 16 + kl * 4 + rg;
        float v = acc[mi][ni][rg] + bv;
        v = (v >= 0.f) ? v : NEG_SLOPE * v;
        if (row < NNODES) C[(size_t)row * HID + col] = f2bf(v);
      }
    }
  }
}

// ---- proj12: t0[n][0:12] = x0[n] @ Pall  (wave per row, P in registers) ----
__global__ __launch_bounds__(256) void proj12(
    const unsigned short* __restrict__ x0h, const float* __restrict__ Pall,
    float* __restrict__ t0) {
  const int lane = threadIdx.x & 63;
  const int wid = blockIdx.x * 4 + (threadIdx.x >> 6);
  const int nw = gridDim.x * 4;
  // per-lane P rows k = lane*8 + i, i<8; 12 floats each = 24 float4
  float4 P[24];
#pragma unroll
  for (int i = 0; i < 8; i++)
#pragma unroll
    for (int c = 0; c < 3; c++)
      P[i * 3 + c] = *reinterpret_cast<const float4*>(Pall + (size_t)(lane * 8 + i) * 12 + c * 4);

  for (int n = wid; n < NNODES; n += nw) {
    uint4 r = *reinterpret_cast<const uint4*>(x0h + (size_t)n * HID + lane * 8);
    float xv[8];
    unsigned int w[4] = {r.x, r.y, r.z, r.w};
#pragma unroll
    for (int d = 0; d < 4; d++) {
      xv[2 * d]     = __builtin_bit_cast(float, w[d] << 16);
      xv[2 * d + 1] = __builtin_bit_cast(float, w[d] & 0xFFFF0000u);
    }
    float acc[12];
#pragma unroll
    for (int j = 0; j < 12; j++) acc[j] = 0.f;
#pragma unroll
    for (int i = 0; i < 8; i++) {
#pragma unroll
      for (int c = 0; c < 3; c++) {
        acc[c * 4 + 0] += xv[i] * P[i * 3 + c].x;
        acc[c * 4 + 1] += xv[i] * P[i * 3 + c].y;
        acc[c * 4 + 2] += xv[i] * P[i * 3 + c].z;
        acc[c * 4 + 3] += xv[i] * P[i * 3 + c].w;
      }
    }
#pragma unroll
    for (int off = 1; off < 64; off <<= 1)
#pragma unroll
      for (int j = 0; j < 12; j++) acc[j] += __shfl_xor(acc[j], off);
    if (lane == 0) {
      float* o = t0 + (size_t)n * 12;
      *reinterpret_cast<float4*>(o)     = {acc[0], acc[1], acc[2], acc[3]};
      *reinterpret_cast<float4*>(o + 4) = {acc[4], acc[5], acc[6], acc[7]};
      *reinterpret_cast<float4*>(o + 8) = {acc[8], acc[9], acc[10], acc[11]};
    }
  }
}

// ---- agg pass 1: s1[n] = mean_src(t0a[src]) + t0b[n] ----
__global__ __launch_bounds__(256) void agg1(
    const float* __restrict__ t0, const int* __restrict__ rp,
    const int* __restrict__ colx, float* __restrict__ s1) {
  const int lane = threadIdx.x & 63;
  const int wid = blockIdx.x * 4 + (threadIdx.x >> 6);
  const int nw = gridDim.x * 4;
  for (int n = wid; n < NNODES; n += nw) {
    int e0 = rp[n], e1 = rp[n + 1];
    float a[4] = {0.f, 0.f, 0.f, 0.f};
    for (int e = e0 + lane; e < e1; e += 64) {
      int s = colx[e];
      float4 v = *reinterpret_cast<const float4*>(t0 + (size_t)s * 12);
      a[0] += v.x; a[1] += v.y; a[2] += v.z; a[3] += v.w;
    }
#pragma unroll
    for (int off = 1; off < 64; off <<= 1)
#pragma unroll
      for (int j = 0; j < 4; j++) a[j] += __shfl_xor(a[j], off);
    if (lane == 0) {
      float sc = (e1 > e0) ? 1.f / (float)(e1 - e0) : 0.f;
      float4 b = *reinterpret_cast<const float4*>(t0 + (size_t)n * 12 + 4);
      float4 o = {a[0] * sc + b.x, a[1] * sc + b.y, a[2] * sc + b.z, a[3] * sc + b.w};
      *reinterpret_cast<float4*>(s1 + (size_t)n * 4) = o;
    }
  }
}

// ---- agg pass 2: out[n] = mean_src(s1[src]) + t0c[n] + ind(n)*kb + kc ----
__global__ __launch_bounds__(256) void agg2(
    const float* __restrict__ s1, const float* __restrict__ t0,
    const int* __restrict__ rp, const int* __restrict__ colx,
    const float* __restrict__ kb, const float* __restrict__ kc,
    float* __restrict__ out) {
  const int lane = threadIdx.x & 63;
  const int wid = blockIdx.x * 4 + (threadIdx.x >> 6);
  const int nw = gridDim.x * 4;
  float4 vb = *reinterpret_cast<const float4*>(kb);
  float4 vc = *reinterpret_cast<const float4*>(kc);
  for (int n = wid; n < NNODES; n += nw) {
    int e0 = rp[n], e1 = rp[n + 1];
    float a[4] = {0.f, 0.f, 0.f, 0.f};
    for (int e = e0 + lane; e < e1; e += 64) {
      int s = colx[e];
      float4 v = *reinterpret_cast<const float4*>(s1 + (size_t)s * 4);
      a[0] += v.x; a[1] += v.y; a[2] += v.z; a[3] += v.w;
    }
#pragma unroll
    for (int off = 1; off < 64; off <<= 1)
#pragma unroll
      for (int j = 0; j < 4; j++) a[j] += __shfl_xor(a[j], off);
    if (lane == 0) {
      float sc = (e1 > e0) ? 1.f / (float)(e1 - e0) : 0.f;
      float ind = (e1 > e0) ? 1.f : 0.f;
      float4 c = *reinterpret_cast<const float4*>(t0 + (size_t)n * 12 + 8);
      float4 o = {a[0] * sc + c.x + ind * vb.x + vc.x,
                  a[1] * sc + c.y + ind * vb.y + vc.y,
                  a[2] * sc + c.z + ind * vb.z + vc.z,
                  a[3] * sc + c.w + ind * vb.w + vc.w};
      *reinterpret_cast<float4*>(out + (size_t)n * 4) = o;
    }
  }
}

extern "C" void kernel_launch(void* const* d_in, const int* in_sizes, int n_in,
                              void* d_out, int out_size, void* d_ws, size_t ws_size,
                              hipStream_t stream) {
  const float* feat = (const float*)d_in[0];
  const int* ei = (const int*)d_in[1];
  const float* W_in = (const float*)d_in[3];
  const float* b_in = (const float*)d_in[4];
  const float* W1l = (const float*)d_in[5];
  const float* b1l = (const float*)d_in[6];
  const float* W1r = (const float*)d_in[7];
  const float* W2l = (const float*)d_in[8];
  const float* b2l = (const float*)d_in[9];
  const float* W2r = (const float*)d_in[10];
  const float* Wout = (const float*)d_in[11];
  const float* bout = (const float*)d_in[12];
  float* out = (float*)d_out;

  // ---- workspace layout, ~62 MB ----
  char* ws = (char*)d_ws;
  size_t off = 0;
  auto alloc = [&](size_t bytes) {
    void* p = ws + off;
    off += (bytes + 15) & ~(size_t)15;
    return p;
  };
  int* flag = (int*)alloc(16);
  int* cnt  = (int*)alloc(NNODES * 4);
  int* next = (int*)alloc(NNODES * 4);
  int* rp   = (int*)alloc((NNODES + 1) * 4);
  int* bsum = (int*)alloc(SCAN_BLOCKS * 4);
  int* boff = (int*)alloc(SCAN_BLOCKS * 4);
  int* colx = (int*)alloc((size_t)NEDGES * 4);
  unsigned short* Wt0 = (unsigned short*)alloc(512 * 512 * 2);
  float* Wlp = (float*)alloc(2048 * 4);
  float* Wrp = (float*)alloc(2048 * 4);
  float* bp  = (float*)alloc(16);
  float* Pall = (float*)alloc(512 * 12 * 4);
  float* kb  = (float*)alloc(16);
  float* kc  = (float*)alloc(16);
  float* t0  = (float*)alloc((size_t)NNODES * 12 * 4);
  float* s1  = (float*)alloc((size_t)NNODES * 4 * 4);
  unsigned short* x0h = (unsigned short*)alloc((size_t)MPAD * HID * 2);
  (void)ws_size;

  // CSR build
  init_misc<<<SCAN_BLOCKS, 256, 0, stream>>>(ei, flag, cnt);
  count_edges<<<(NEDGES + 255) / 256, 256, 0, stream>>>(ei, flag, cnt);
  scan_a<<<SCAN_BLOCKS, 256, 0, stream>>>(cnt, bsum);
  scan_b<<<1, 256, 0, stream>>>(bsum, boff, rp);
  scan_c<<<SCAN_BLOCKS, 256, 0, stream>>>(cnt, boff, rp, next);
  scatter_edges<<<(NEDGES + 255) / 256, 256, 0, stream>>>(ei, flag, next, colx);

  // weight prep
  tcast<<<1024, 256, 0, stream>>>(W_in, Wt0);
  smallA<<<1025, 256, 0, stream>>>(W2l, W2r, Wout, b2l, bout, Wlp, Wrp, bp);
  smallB<<<1538, 256, 0, stream>>>(W1l, W1r, b1l, Wlp, Wrp, bp, Pall, kb, kc);

  // pipeline
  gemm1<<<(MPAD / 128) * 4, 256, 0, stream>>>(feat, Wt0, b_in, x0h);
  proj12<<<1024, 256, 0, stream>>>(x0h, Pall, t0);
  agg1<<<2048, 256, 0, stream>>>(t0, rp, colx, s1);
  agg2<<<2048, 256, 0, stream>>>(s1, t0, rp, colx, kb, kc, out);
}

// Round 4
// 349.180 us; speedup vs baseline: 2.2666x; 1.1981x over previous
//
#include <hip/hip_runtime.h>
#include <stdint.h>

#define NNODES 50000
#define NEDGES 1600000
#define HID 512
#define MPAD 50048   // 391*128
#define NEG_SLOPE 0.01f
#define NBUCK 98     // dst>>9 buckets (512 nodes each)
#define NBLK 200     // partition blocks
#define TILE 8000    // NEDGES / NBLK
#define NSUB 8       // agg sub-blocks per bucket

typedef __attribute__((ext_vector_type(8))) short bf16x8;
typedef __attribute__((ext_vector_type(8))) unsigned short u16x8;
typedef __attribute__((ext_vector_type(4))) float f32x4;

__device__ __forceinline__ float bf2f(unsigned short u) {
  unsigned int x = ((unsigned int)u) << 16;
  return __builtin_bit_cast(float, x);
}
__device__ __forceinline__ unsigned short f2bf(float f) {
  unsigned int u = __builtin_bit_cast(unsigned int, f);
  u += 0x7FFFu + ((u >> 16) & 1u);
  return (unsigned short)(u >> 16);
}
__device__ __forceinline__ void gload_lds16(const void* g, void* l) {
  __builtin_amdgcn_global_load_lds(
      (const __attribute__((address_space(1))) void*)g,
      (__attribute__((address_space(3))) void*)l, 16, 0, 0);
}

// ---- detect edge_index storage (int32 vs int64-as-u32-pairs) ----
__global__ void flagk(const int* __restrict__ ei, int* __restrict__ flag) {
  int t = threadIdx.x;
  unsigned long long m = __ballot(ei[2 * t + 1] != 0);
  if (t == 0) *flag = (m != 0ULL) ? 1 : 0;
}

// ---- per-block bucket histogram: hist[b*NBLK + blk] ----
__global__ __launch_bounds__(256) void histk(const int* __restrict__ ei,
                                             const int* __restrict__ flag,
                                             int* __restrict__ hist) {
  __shared__ int h[NBUCK];
  int t = threadIdx.x, blk = blockIdx.x;
  for (int i = t; i < NBUCK; i += 256) h[i] = 0;
  __syncthreads();
  int f = *flag;
  int e0 = blk * TILE;
  for (int e = e0 + t; e < e0 + TILE; e += 256) {
    int d = f ? ei[(size_t)NEDGES + e] : ei[2 * ((size_t)NEDGES + e)];
    if ((unsigned)d < NNODES) atomicAdd(&h[d >> 9], 1);
  }
  __syncthreads();
  for (int i = t; i < NBUCK; i += 256) hist[i * NBLK + blk] = h[i];
}

// ---- single-block exclusive scan of hist (bucket-major) -> bases + bstart ----
__global__ __launch_bounds__(512) void scanh(int* __restrict__ hist,
                                             int* __restrict__ bstart) {
  __shared__ int s[512];
  const int TOT = NBUCK * NBLK;  // 19600
  const int C = 40;              // 512*40 = 20480 >= TOT
  int t = threadIdx.x;
  int base = t * C;
  int sum = 0;
#pragma unroll
  for (int i = 0; i < C; i++) {
    int idx = base + i;
    sum += (idx < TOT) ? hist[idx] : 0;
  }
  s[t] = sum;
  __syncthreads();
  for (int off = 1; off < 512; off <<= 1) {
    int u = (t >= off) ? s[t - off] : 0;
    __syncthreads();
    s[t] += u;
    __syncthreads();
  }
  int run = (t > 0) ? s[t - 1] : 0;
#pragma unroll
  for (int i = 0; i < C; i++) {
    int idx = base + i;
    if (idx < TOT) {
      int v = hist[idx];
      hist[idx] = run;
      if (idx % NBLK == 0) bstart[idx / NBLK] = run;
      run += v;
    }
  }
  if (t == 511) bstart[NBUCK] = s[511];
}

// ---- bucketed scatter: packed (dst&511)<<16 | src, LDS-local positions ----
__global__ __launch_bounds__(256) void binscatter(const int* __restrict__ ei,
                                                  const int* __restrict__ flag,
                                                  const int* __restrict__ hbase,
                                                  unsigned int* __restrict__ pcol) {
  __shared__ int lb[NBUCK];
  int t = threadIdx.x, blk = blockIdx.x;
  for (int i = t; i < NBUCK; i += 256) lb[i] = hbase[i * NBLK + blk];
  __syncthreads();
  int f = *flag;
  int e0 = blk * TILE;
  for (int e = e0 + t; e < e0 + TILE; e += 256) {
    int sN = f ? ei[e] : ei[2 * (size_t)e];
    int d  = f ? ei[(size_t)NEDGES + e] : ei[2 * ((size_t)NEDGES + e)];
    if ((unsigned)d >= NNODES) continue;
    if ((unsigned)sN >= NNODES) sN = 0;
    int pos = atomicAdd(&lb[d >> 9], 1);
    pcol[pos] = ((unsigned)(d & 511) << 16) | (unsigned)sN;
  }
}

// ---- Wt0[n][k] = bf16(W_in[k][n]) ----
__global__ void tcast(const float* __restrict__ w, unsigned short* __restrict__ wt) {
  int i = blockIdx.x * 256 + threadIdx.x;  // 262144
  int n = i >> 9, k = i & 511;
  wt[i] = f2bf(w[(k << 9) | n]);
}

// ---- wave-parallel 512-dot ----
__device__ __forceinline__ float wave_dot(const float* __restrict__ Arow,
                                          const float* __restrict__ B, int j) {
  int l = threadIdx.x & 63;
  float4 a0 = *reinterpret_cast<const float4*>(Arow + l * 8);
  float4 a1 = *reinterpret_cast<const float4*>(Arow + l * 8 + 4);
  const float* bb = B + (size_t)(l * 8) * 4 + j;
  float s = a0.x * bb[0] + a0.y * bb[4] + a0.z * bb[8] + a0.w * bb[12] +
            a1.x * bb[16] + a1.y * bb[20] + a1.z * bb[24] + a1.w * bb[28];
#pragma unroll
  for (int off = 1; off < 64; off <<= 1) s += __shfl_xor(s, off);
  return s;
}

__global__ __launch_bounds__(256) void smallA(
    const float* __restrict__ W2l, const float* __restrict__ W2r,
    const float* __restrict__ Wout, const float* __restrict__ b2l,
    const float* __restrict__ bout,
    float* __restrict__ Wlp, float* __restrict__ Wrp, float* __restrict__ bp) {
  int gw = blockIdx.x * 4 + (threadIdx.x >> 6);
  int l = threadIdx.x & 63;
  if (gw < 2048) {
    float v = wave_dot(W2l + (size_t)(gw >> 2) * 512, Wout, gw & 3);
    if (l == 0) Wlp[gw] = v;
  } else if (gw < 4096) {
    int g = gw - 2048;
    float v = wave_dot(W2r + (size_t)(g >> 2) * 512, Wout, g & 3);
    if (l == 0) Wrp[g] = v;
  } else if (gw < 4100) {
    int j = gw - 4096;
    float v = wave_dot(b2l, Wout, j);
    if (l == 0) bp[j] = v + bout[j];
  }
}

__global__ __launch_bounds__(256) void smallB(
    const float* __restrict__ W1l, const float* __restrict__ W1r,
    const float* __restrict__ b1l,
    const float* __restrict__ Wlp, const float* __restrict__ Wrp,
    const float* __restrict__ bp,
    float* __restrict__ Pall, float* __restrict__ kb, float* __restrict__ kc) {
  int gw = blockIdx.x * 4 + (threadIdx.x >> 6);
  int l = threadIdx.x & 63;
  if (gw < 6144) {
    int k = gw / 12, jg = gw % 12;
    int g = jg >> 2, j = jg & 3;
    float v;
    if (g == 0) v = wave_dot(W1l + (size_t)k * 512, Wlp, j);
    else if (g == 1) v = wave_dot(W1r + (size_t)k * 512, Wlp, j) +
                         wave_dot(W1l + (size_t)k * 512, Wrp, j);
    else v = wave_dot(W1r + (size_t)k * 512, Wrp, j);
    if (l == 0) Pall[k * 12 + jg] = v;
  } else if (gw < 6152) {
    int i = gw - 6144, j = i & 3;
    if (i < 4) {
      float v = wave_dot(b1l, Wlp, j);
      if (l == 0) kb[j] = v;
    } else {
      float v = wave_dot(b1l, Wrp, j);
      if (l == 0) kc[j] = v + bp[j];
    }
  }
}

// ---- GEMM1: x0 = leaky(feat(fp32) @ W_in + b_in) -> bf16 [rows<NNODES][512] ----
__global__ __launch_bounds__(256) void gemm1(
    const float* __restrict__ A, const unsigned short* __restrict__ Bt,
    const float* __restrict__ bias, unsigned short* __restrict__ C) {
  __shared__ unsigned short As[128 * 32];
  __shared__ unsigned short Bs[128 * 32];
  const int tid = threadIdx.x;
  const int wave = tid >> 6, lane = tid & 63;
  const int bid = blockIdx.x;
  const int bm = (bid >> 2) * 128, bn = (bid & 3) * 128;
  const int wr = wave >> 1, wc = wave & 1;
  const int r15 = lane & 15, kl = lane >> 4;
  const int srow = lane >> 2, soff = (lane & 3) * 8;

  f32x4 acc[4][4];
#pragma unroll
  for (int i = 0; i < 4; i++)
#pragma unroll
    for (int j = 0; j < 4; j++) acc[i][j] = {0.f, 0.f, 0.f, 0.f};

  for (int kt = 0; kt < HID / 32; ++kt) {
#pragma unroll
    for (int rr = 0; rr < 2; ++rr) {
      int c = wave * 2 + rr;
      int row = c * 16 + srow;
      gload_lds16(Bt + (size_t)(bn + row) * HID + kt * 32 + soff, (void*)&Bs[c * 512]);
    }
#pragma unroll
    for (int ss = 0; ss < 2; ++ss) {
      int s = tid + ss * 256;
      int row = s >> 2, k8 = (s & 3) * 8;
      int garow = bm + row;
      if (garow >= NNODES) garow = 0;
      const float* ga = A + (size_t)garow * HID + kt * 32 + k8;
      float4 v0 = *reinterpret_cast<const float4*>(ga);
      float4 v1 = *reinterpret_cast<const float4*>(ga + 4);
      u16x8 pk;
      pk[0] = f2bf(v0.x); pk[1] = f2bf(v0.y); pk[2] = f2bf(v0.z); pk[3] = f2bf(v0.w);
      pk[4] = f2bf(v1.x); pk[5] = f2bf(v1.y); pk[6] = f2bf(v1.z); pk[7] = f2bf(v1.w);
      *reinterpret_cast<u16x8*>(&As[row * 32 + k8]) = pk;
    }
    __syncthreads();
    bf16x8 af[4], bfr[4];
#pragma unroll
    for (int mi = 0; mi < 4; ++mi)
      af[mi] = *reinterpret_cast<const bf16x8*>(&As[(wr * 64 + mi * 16 + r15) * 32 + kl * 8]);
#pragma unroll
    for (int ni = 0; ni < 4; ++ni)
      bfr[ni] = *reinterpret_cast<const bf16x8*>(&Bs[(wc * 64 + ni * 16 + r15) * 32 + kl * 8]);
#pragma unroll
    for (int mi = 0; mi < 4; ++mi)
#pragma unroll
      for (int ni = 0; ni < 4; ++ni)
        acc[mi][ni] = __builtin_amdgcn_mfma_f32_16x16x32_bf16(af[mi], bfr[ni], acc[mi][ni], 0, 0, 0);
    __syncthreads();
  }
#pragma unroll
  for (int ni = 0; ni < 4; ++ni) {
    int col = bn + wc * 64 + ni * 16 + r15;
    float bv = bias[col];
#pragma unroll
    for (int mi = 0; mi < 4; ++mi) {
#pragma unroll
      for (int rg = 0; rg < 4; ++rg) {
        int row = bm + wr * 64 + mi * 16 + kl * 4 + rg;
        float v = acc[mi][ni][rg] + bv;
        v = (v >= 0.f) ? v : NEG_SLOPE * v;
        if (row < NNODES) C[(size_t)row * HID + col] = f2bf(v);
      }
    }
  }
}

// ---- proj12: t0[n][0:12] = x0[n] @ Pall  (wave per row, P in registers) ----
__global__ __launch_bounds__(256) void proj12(
    const unsigned short* __restrict__ x0h, const float* __restrict__ Pall,
    float* __restrict__ t0) {
  const int lane = threadIdx.x & 63;
  const int wid = blockIdx.x * 4 + (threadIdx.x >> 6);
  const int nw = gridDim.x * 4;
  float4 P[24];
#pragma unroll
  for (int i = 0; i < 8; i++)
#pragma unroll
    for (int c = 0; c < 3; c++)
      P[i * 3 + c] = *reinterpret_cast<const float4*>(Pall + (size_t)(lane * 8 + i) * 12 + c * 4);

  for (int n = wid; n < NNODES; n += nw) {
    uint4 r = *reinterpret_cast<const uint4*>(x0h + (size_t)n * HID + lane * 8);
    float xv[8];
    unsigned int w[4] = {r.x, r.y, r.z, r.w};
#pragma unroll
    for (int d = 0; d < 4; d++) {
      xv[2 * d]     = __builtin_bit_cast(float, w[d] << 16);
      xv[2 * d + 1] = __builtin_bit_cast(float, w[d] & 0xFFFF0000u);
    }
    float acc[12];
#pragma unroll
    for (int j = 0; j < 12; j++) acc[j] = 0.f;
#pragma unroll
    for (int i = 0; i < 8; i++) {
#pragma unroll
      for (int c = 0; c < 3; c++) {
        acc[c * 4 + 0] += xv[i] * P[i * 3 + c].x;
        acc[c * 4 + 1] += xv[i] * P[i * 3 + c].y;
        acc[c * 4 + 2] += xv[i] * P[i * 3 + c].z;
        acc[c * 4 + 3] += xv[i] * P[i * 3 + c].w;
      }
    }
#pragma unroll
    for (int off = 1; off < 64; off <<= 1)
#pragma unroll
      for (int j = 0; j < 12; j++) acc[j] += __shfl_xor(acc[j], off);
    if (lane == 0) {
      float* o = t0 + (size_t)n * 12;
      *reinterpret_cast<float4*>(o)     = {acc[0], acc[1], acc[2], acc[3]};
      *reinterpret_cast<float4*>(o + 4) = {acc[4], acc[5], acc[6], acc[7]};
      *reinterpret_cast<float4*>(o + 8) = {acc[8], acc[9], acc[10], acc[11]};
    }
  }
}

// ---- agg pass 1 (bucketed LDS accumulate): vals = t0a[src], + degree count ----
__global__ __launch_bounds__(256) void aggA(
    const unsigned int* __restrict__ pcol, const int* __restrict__ bstart,
    const float* __restrict__ t0, float* __restrict__ partial) {
  __shared__ float tab[512 * 5];
  int t = threadIdx.x;
  int b = blockIdx.x >> 3, sb = blockIdx.x & 7;
  for (int i = t; i < 2560; i += 256) tab[i] = 0.f;
  __syncthreads();
  int st = bstart[b], en = bstart[b + 1];
  int len = en - st;
  int a0 = st + (int)(((long long)len * sb) >> 3);
  int a1 = st + (int)(((long long)len * (sb + 1)) >> 3);
  for (int e = a0 + t; e < a1; e += 256) {
    unsigned v = pcol[e];
    int i = v >> 16, src = v & 0xFFFF;
    float4 x = *reinterpret_cast<const float4*>(t0 + (size_t)src * 12);
    atomicAdd(&tab[i * 5 + 0], x.x);
    atomicAdd(&tab[i * 5 + 1], x.y);
    atomicAdd(&tab[i * 5 + 2], x.z);
    atomicAdd(&tab[i * 5 + 3], x.w);
    atomicAdd(&tab[i * 5 + 4], 1.f);
  }
  __syncthreads();
  float* o = partial + (size_t)blockIdx.x * 2560;
  for (int i = t; i < 2560; i += 256) o[i] = tab[i];
}

// ---- fin pass 1: s1[n] = sum/deg + t0b[n]; store deg ----
__global__ __launch_bounds__(256) void finA(
    const float* __restrict__ partial, const float* __restrict__ t0,
    float* __restrict__ s1, float* __restrict__ degf) {
  int n = blockIdx.x * 256 + threadIdx.x;
  if (n >= NNODES) return;
  int b = n >> 9, i = n & 511;
  float a[5] = {0.f, 0.f, 0.f, 0.f, 0.f};
#pragma unroll
  for (int s = 0; s < 8; s++) {
    const float* p = partial + (size_t)(b * 8 + s) * 2560 + i * 5;
#pragma unroll
    for (int j = 0; j < 5; j++) a[j] += p[j];
  }
  float deg = a[4];
  float sc = (deg > 0.f) ? 1.f / deg : 0.f;
  float4 tb = *reinterpret_cast<const float4*>(t0 + (size_t)n * 12 + 4);
  float4 o = {a[0] * sc + tb.x, a[1] * sc + tb.y, a[2] * sc + tb.z, a[3] * sc + tb.w};
  *reinterpret_cast<float4*>(s1 + (size_t)n * 4) = o;
  degf[n] = deg;
}

// ---- agg pass 2: vals = s1[src] ----
__global__ __launch_bounds__(256) void aggB(
    const unsigned int* __restrict__ pcol, const int* __restrict__ bstart,
    const float* __restrict__ s1, float* __restrict__ partial) {
  __shared__ float tab[512 * 4];
  int t = threadIdx.x;
  int b = blockIdx.x >> 3, sb = blockIdx.x & 7;
  for (int i = t; i < 2048; i += 256) tab[i] = 0.f;
  __syncthreads();
  int st = bstart[b], en = bstart[b + 1];
  int len = en - st;
  int a0 = st + (int)(((long long)len * sb) >> 3);
  int a1 = st + (int)(((long long)len * (sb + 1)) >> 3);
  for (int e = a0 + t; e < a1; e += 256) {
    unsigned v = pcol[e];
    int i = v >> 16, src = v & 0xFFFF;
    float4 x = *reinterpret_cast<const float4*>(s1 + (size_t)src * 4);
    atomicAdd(&tab[i * 4 + 0], x.x);
    atomicAdd(&tab[i * 4 + 1], x.y);
    atomicAdd(&tab[i * 4 + 2], x.z);
    atomicAdd(&tab[i * 4 + 3], x.w);
  }
  __syncthreads();
  float* o = partial + (size_t)blockIdx.x * 2048;
  for (int i = t; i < 2048; i += 256) o[i] = tab[i];
}

// ---- fin pass 2: out[n] = sum/deg + t0c[n] + ind*kb + kc ----
__global__ __launch_bounds__(256) void finB(
    const float* __restrict__ partial, const float* __restrict__ t0,
    const float* __restrict__ degf, const float* __restrict__ kb,
    const float* __restrict__ kc, float* __restrict__ out) {
  int n = blockIdx.x * 256 + threadIdx.x;
  if (n >= NNODES) return;
  int b = n >> 9, i = n & 511;
  float a[4] = {0.f, 0.f, 0.f, 0.f};
#pragma unroll
  for (int s = 0; s < 8; s++) {
    const float* p = partial + (size_t)(b * 8 + s) * 2048 + i * 4;
#pragma unroll
    for (int j = 0; j < 4; j++) a[j] += p[j];
  }
  float deg = degf[n];
  float sc = (deg > 0.f) ? 1.f / deg : 0.f;
  float ind = (deg > 0.f) ? 1.f : 0.f;
  float4 c = *reinterpret_cast<const float4*>(t0 + (size_t)n * 12 + 8);
  float4 vb = *reinterpret_cast<const float4*>(kb);
  float4 vc = *reinterpret_cast<const float4*>(kc);
  float4 o = {a[0] * sc + c.x + ind * vb.x + vc.x,
              a[1] * sc + c.y + ind * vb.y + vc.y,
              a[2] * sc + c.z + ind * vb.z + vc.z,
              a[3] * sc + c.w + ind * vb.w + vc.w};
  *reinterpret_cast<float4*>(out + (size_t)n * 4) = o;
}

extern "C" void kernel_launch(void* const* d_in, const int* in_sizes, int n_in,
                              void* d_out, int out_size, void* d_ws, size_t ws_size,
                              hipStream_t stream) {
  const float* feat = (const float*)d_in[0];
  const int* ei = (const int*)d_in[1];
  const float* W_in = (const float*)d_in[3];
  const float* b_in = (const float*)d_in[4];
  const float* W1l = (const float*)d_in[5];
  const float* b1l = (const float*)d_in[6];
  const float* W1r = (const float*)d_in[7];
  const float* W2l = (const float*)d_in[8];
  const float* b2l = (const float*)d_in[9];
  const float* W2r = (const float*)d_in[10];
  const float* Wout = (const float*)d_in[11];
  const float* bout = (const float*)d_in[12];
  float* out = (float*)d_out;

  // ---- workspace layout, ~70 MB ----
  char* ws = (char*)d_ws;
  size_t off = 0;
  auto alloc = [&](size_t bytes) {
    void* p = ws + off;
    off += (bytes + 15) & ~(size_t)15;
    return p;
  };
  int* flag   = (int*)alloc(16);
  int* hist   = (int*)alloc((size_t)NBUCK * NBLK * 4);   // in-place scanned to bases
  int* bstart = (int*)alloc((NBUCK + 1) * 4);
  unsigned int* pcol = (unsigned int*)alloc((size_t)NEDGES * 4);
  unsigned short* Wt0 = (unsigned short*)alloc(512 * 512 * 2);
  float* Wlp  = (float*)alloc(2048 * 4);
  float* Wrp  = (float*)alloc(2048 * 4);
  float* bp   = (float*)alloc(16);
  float* Pall = (float*)alloc(512 * 12 * 4);
  float* kb   = (float*)alloc(16);
  float* kc   = (float*)alloc(16);
  float* t0   = (float*)alloc((size_t)NNODES * 12 * 4);
  float* s1   = (float*)alloc((size_t)NNODES * 4 * 4);
  float* degf = (float*)alloc((size_t)NNODES * 4);
  float* partial = (float*)alloc((size_t)NBUCK * NSUB * 2560 * 4);  // A; B aliases
  unsigned short* x0h = (unsigned short*)alloc((size_t)MPAD * HID * 2);
  (void)ws_size;

  // graph partition (replaces CSR build)
  flagk<<<1, 64, 0, stream>>>(ei, flag);
  histk<<<NBLK, 256, 0, stream>>>(ei, flag, hist);
  scanh<<<1, 512, 0, stream>>>(hist, bstart);
  binscatter<<<NBLK, 256, 0, stream>>>(ei, flag, hist, pcol);

  // weight prep
  tcast<<<1024, 256, 0, stream>>>(W_in, Wt0);
  smallA<<<1025, 256, 0, stream>>>(W2l, W2r, Wout, b2l, bout, Wlp, Wrp, bp);
  smallB<<<1538, 256, 0, stream>>>(W1l, W1r, b1l, Wlp, Wrp, bp, Pall, kb, kc);

  // pipeline
  gemm1<<<(MPAD / 128) * 4, 256, 0, stream>>>(feat, Wt0, b_in, x0h);
  proj12<<<1024, 256, 0, stream>>>(x0h, Pall, t0);
  aggA<<<NBUCK * NSUB, 256, 0, stream>>>(pcol, bstart, t0, partial);
  finA<<<(NNODES + 255) / 256, 256, 0, stream>>>(partial, t0, s1, degf);
  aggB<<<NBUCK * NSUB, 256, 0, stream>>>(pcol, bstart, s1, partial);
  finB<<<(NNODES + 255) / 256, 256, 0, stream>>>(partial, t0, degf, kb, kc, out);
}

// Round 6
// 284.453 us; speedup vs baseline: 2.7824x; 1.2275x over previous
//
#include <hip/hip_runtime.h>
#include <stdint.h>

#define NNODES 50000
#define NEDGES 1600000
#define HID 512
#define NEG_SLOPE 0.01f
#define NBUCK 98     // dst>>9 buckets (512 nodes each)
#define NBLK 200     // partition blocks
#define TILE 8000    // NEDGES / NBLK
#define NSUB 8       // agg sub-blocks per bucket
#define GPBLK 391    // ceil(50000/128)

typedef __attribute__((ext_vector_type(8))) short bf16x8;
typedef __attribute__((ext_vector_type(8))) unsigned short u16x8;
typedef __attribute__((ext_vector_type(4))) float f32x4;

__device__ __forceinline__ float bf2f(unsigned short u) {
  unsigned int x = ((unsigned int)u) << 16;
  return __builtin_bit_cast(float, x);
}
__device__ __forceinline__ unsigned short f2bf(float f) {
  unsigned int u = __builtin_bit_cast(unsigned int, f);
  u += 0x7FFFu + ((u >> 16) & 1u);
  return (unsigned short)(u >> 16);
}

// ---- detect edge_index storage (int32 vs int64-as-u32-pairs) ----
__global__ void flagk(const int* __restrict__ ei, int* __restrict__ flag) {
  int t = threadIdx.x;
  unsigned long long m = __ballot(ei[2 * t + 1] != 0);
  if (t == 0) *flag = (m != 0ULL) ? 1 : 0;
}

// ---- per-block bucket histogram: hist[b*NBLK + blk] ----
__global__ __launch_bounds__(256) void histk(const int* __restrict__ ei,
                                             const int* __restrict__ flag,
                                             int* __restrict__ hist) {
  __shared__ int h[NBUCK];
  int t = threadIdx.x, blk = blockIdx.x;
  for (int i = t; i < NBUCK; i += 256) h[i] = 0;
  __syncthreads();
  int f = *flag;
  int e0 = blk * TILE;
  for (int e = e0 + 2 * t; e < e0 + TILE; e += 512) {
    int d0, d1;
    if (f) {
      int2 v = *reinterpret_cast<const int2*>(&ei[(size_t)NEDGES + e]);
      d0 = v.x; d1 = v.y;
    } else {
      int4 v = *reinterpret_cast<const int4*>(&ei[2 * ((size_t)NEDGES + e)]);
      d0 = v.x; d1 = v.z;
    }
    if ((unsigned)d0 < NNODES) atomicAdd(&h[d0 >> 9], 1);
    if ((unsigned)d1 < NNODES) atomicAdd(&h[d1 >> 9], 1);
  }
  __syncthreads();
  for (int i = t; i < NBUCK; i += 256) hist[i * NBLK + blk] = h[i];
}

// ---- single-block exclusive scan of hist (bucket-major) -> bases + bstart ----
__global__ __launch_bounds__(512) void scanh(int* __restrict__ hist,
                                             int* __restrict__ bstart) {
  __shared__ int s[512];
  const int TOT = NBUCK * NBLK;  // 19600
  const int C = 40;
  int t = threadIdx.x;
  int base = t * C;
  int sum = 0;
#pragma unroll
  for (int i = 0; i < C; i++) {
    int idx = base + i;
    sum += (idx < TOT) ? hist[idx] : 0;
  }
  s[t] = sum;
  __syncthreads();
  for (int off = 1; off < 512; off <<= 1) {
    int u = (t >= off) ? s[t - off] : 0;
    __syncthreads();
    s[t] += u;
    __syncthreads();
  }
  int run = (t > 0) ? s[t - 1] : 0;
#pragma unroll
  for (int i = 0; i < C; i++) {
    int idx = base + i;
    if (idx < TOT) {
      int v = hist[idx];
      hist[idx] = run;
      if (idx % NBLK == 0) bstart[idx / NBLK] = run;
      run += v;
    }
  }
  if (t == 511) bstart[NBUCK] = s[511];
}

// ---- bucketed scatter: packed (dst&511)<<16 | src, LDS-local positions ----
__global__ __launch_bounds__(256) void binscatter(const int* __restrict__ ei,
                                                  const int* __restrict__ flag,
                                                  const int* __restrict__ hbase,
                                                  unsigned int* __restrict__ pcol) {
  __shared__ int lb[NBUCK];
  int t = threadIdx.x, blk = blockIdx.x;
  for (int i = t; i < NBUCK; i += 256) lb[i] = hbase[i * NBLK + blk];
  __syncthreads();
  int f = *flag;
  int e0 = blk * TILE;
  for (int e = e0 + 2 * t; e < e0 + TILE; e += 512) {
    int s0, s1, d0, d1;
    if (f) {
      int2 vs = *reinterpret_cast<const int2*>(&ei[e]);
      int2 vd = *reinterpret_cast<const int2*>(&ei[(size_t)NEDGES + e]);
      s0 = vs.x; s1 = vs.y; d0 = vd.x; d1 = vd.y;
    } else {
      int4 vs = *reinterpret_cast<const int4*>(&ei[2 * (size_t)e]);
      int4 vd = *reinterpret_cast<const int4*>(&ei[2 * ((size_t)NEDGES + e)]);
      s0 = vs.x; s1 = vs.z; d0 = vd.x; d1 = vd.z;
    }
    if ((unsigned)d0 < NNODES) {
      if ((unsigned)s0 >= NNODES) s0 = 0;
      int pos = atomicAdd(&lb[d0 >> 9], 1);
      pcol[pos] = ((unsigned)(d0 & 511) << 16) | (unsigned)s0;
    }
    if ((unsigned)d1 < NNODES) {
      if ((unsigned)s1 >= NNODES) s1 = 0;
      int pos = atomicAdd(&lb[d1 >> 9], 1);
      pcol[pos] = ((unsigned)(d1 & 511) << 16) | (unsigned)s1;
    }
  }
}

// ---- Wt0[n][k] = bf16(W_in[k][n]) ----
__global__ void tcast(const float* __restrict__ w, unsigned short* __restrict__ wt) {
  int i = blockIdx.x * 256 + threadIdx.x;  // 262144
  int n = i >> 9, k = i & 511;
  wt[i] = f2bf(w[(k << 9) | n]);
}

// ---- wave-parallel 512-dot ----
__device__ __forceinline__ float wave_dot(const float* __restrict__ Arow,
                                          const float* __restrict__ B, int j) {
  int l = threadIdx.x & 63;
  float4 a0 = *reinterpret_cast<const float4*>(Arow + l * 8);
  float4 a1 = *reinterpret_cast<const float4*>(Arow + l * 8 + 4);
  const float* bb = B + (size_t)(l * 8) * 4 + j;
  float s = a0.x * bb[0] + a0.y * bb[4] + a0.z * bb[8] + a0.w * bb[12] +
            a1.x * bb[16] + a1.y * bb[20] + a1.z * bb[24] + a1.w * bb[28];
#pragma unroll
  for (int off = 1; off < 64; off <<= 1) s += __shfl_xor(s, off);
  return s;
}

__global__ __launch_bounds__(256) void smallA(
    const float* __restrict__ W2l, const float* __restrict__ W2r,
    const float* __restrict__ Wout, const float* __restrict__ b2l,
    const float* __restrict__ bout,
    float* __restrict__ Wlp, float* __restrict__ Wrp, float* __restrict__ bp) {
  int gw = blockIdx.x * 4 + (threadIdx.x >> 6);
  int l = threadIdx.x & 63;
  if (gw < 2048) {
    float v = wave_dot(W2l + (size_t)(gw >> 2) * 512, Wout, gw & 3);
    if (l == 0) Wlp[gw] = v;
  } else if (gw < 4096) {
    int g = gw - 2048;
    float v = wave_dot(W2r + (size_t)(g >> 2) * 512, Wout, g & 3);
    if (l == 0) Wrp[g] = v;
  } else if (gw < 4100) {
    int j = gw - 4096;
    float v = wave_dot(b2l, Wout, j);
    if (l == 0) bp[j] = v + bout[j];
  }
}

__global__ __launch_bounds__(256) void smallB(
    const float* __restrict__ W1l, const float* __restrict__ W1r,
    const float* __restrict__ b1l,
    const float* __restrict__ Wlp, const float* __restrict__ Wrp,
    const float* __restrict__ bp,
    float* __restrict__ Pall, float* __restrict__ kb, float* __restrict__ kc) {
  int gw = blockIdx.x * 4 + (threadIdx.x >> 6);
  int l = threadIdx.x & 63;
  if (gw < 6144) {
    int k = gw / 12, jg = gw % 12;
    int g = jg >> 2, j = jg & 3;
    float v;
    if (g == 0) v = wave_dot(W1l + (size_t)k * 512, Wlp, j);
    else if (g == 1) v = wave_dot(W1r + (size_t)k * 512, Wlp, j) +
                         wave_dot(W1l + (size_t)k * 512, Wrp, j);
    else v = wave_dot(W1r + (size_t)k * 512, Wrp, j);
    if (l == 0) Pall[k * 12 + jg] = v;
  } else if (gw < 6152) {
    int i = gw - 6144, j = i & 3;
    if (i < 4) {
      float v = wave_dot(b1l, Wlp, j);
      if (l == 0) kb[j] = v;
    } else {
      float v = wave_dot(b1l, Wrp, j);
      if (l == 0) kc[j] = v + bp[j];
    }
  }
}

// ---- fused GEMM1 + 12-col projection (no x0 materialization) ----
// Block: 128 rows x 512 cols of x0 = leaky(feat@W_in + b_in).
// Swapped-operand MFMA: mfma(bfr, af) -> D'[i][j] = C[row=j(r15)][col=i(kl*4+reg)].
// Projection done in fp32 straight from accumulators; reduce kl via shfl,
// reduce the 4 wc-waves via LDS atomics into tab[128][12].
__global__ __launch_bounds__(512) void gemmproj(
    const float* __restrict__ A, const unsigned short* __restrict__ Bt,
    const float* __restrict__ bias, const float* __restrict__ Pall,
    float* __restrict__ t0) {
  __shared__ __align__(16) char smem[51200];
  unsigned short* As = (unsigned short*)smem;            // [128][40] padded
  unsigned short* Bs = (unsigned short*)(smem + 10240);  // [512][40] padded
  __shared__ float tab[128 * 12];
  const int tid = threadIdx.x;
  const int wv = tid >> 6, lane = tid & 63;
  const int bm = blockIdx.x * 128;
  const int wr = wv >> 2, wc = wv & 3;
  const int r15 = lane & 15, kl = lane >> 4;

  for (int i = tid; i < 1536; i += 512) tab[i] = 0.f;

  f32x4 acc[8][4];  // [ni][mi]
#pragma unroll
  for (int ni = 0; ni < 8; ni++)
#pragma unroll
    for (int mi = 0; mi < 4; mi++) acc[ni][mi] = {0.f, 0.f, 0.f, 0.f};

  const int arow = tid >> 2;        // 0..127
  const int ak8 = (tid & 3) * 8;
  int garow = bm + arow;
  if (garow >= NNODES) garow = 0;   // pad rows, discarded at t0 write
  const float* gabase = A + (size_t)garow * HID + ak8;

  for (int kt = 0; kt < 16; ++kt) {
    // A: fp32 -> bf16 -> LDS (padded rows: 40 ushorts)
    const float* ga = gabase + kt * 32;
    float4 v0 = *reinterpret_cast<const float4*>(ga);
    float4 v1 = *reinterpret_cast<const float4*>(ga + 4);
    u16x8 pk;
    pk[0] = f2bf(v0.x); pk[1] = f2bf(v0.y); pk[2] = f2bf(v0.z); pk[3] = f2bf(v0.w);
    pk[4] = f2bf(v1.x); pk[5] = f2bf(v1.y); pk[6] = f2bf(v1.z); pk[7] = f2bf(v1.w);
    *reinterpret_cast<u16x8*>(&As[arow * 40 + ak8]) = pk;
    // B: bf16 tile [512][32] -> LDS padded
#pragma unroll
    for (int i = 0; i < 4; ++i) {
      int c = i * 512 + tid;
      int n = c >> 2, slot = c & 3;
      uint4 bv = *reinterpret_cast<const uint4*>(Bt + (size_t)n * HID + kt * 32 + slot * 8);
      *reinterpret_cast<uint4*>(&Bs[n * 40 + slot * 8]) = bv;
    }
    __syncthreads();
    bf16x8 af[4], bfr[8];
#pragma unroll
    for (int mi = 0; mi < 4; ++mi)
      af[mi] = *reinterpret_cast<const bf16x8*>(&As[(wr * 64 + mi * 16 + r15) * 40 + kl * 8]);
#pragma unroll
    for (int ni = 0; ni < 8; ++ni)
      bfr[ni] = *reinterpret_cast<const bf16x8*>(&Bs[(wc * 128 + ni * 16 + r15) * 40 + kl * 8]);
#pragma unroll
    for (int ni = 0; ni < 8; ++ni)
#pragma unroll
      for (int mi = 0; mi < 4; ++mi)
        acc[ni][mi] = __builtin_amdgcn_mfma_f32_16x16x32_bf16(bfr[ni], af[mi], acc[ni][mi], 0, 0, 0);
    __syncthreads();
  }

  // ---- projection epilogue, fp32, straight from acc ----
  float part[4][12];
#pragma unroll
  for (int mi = 0; mi < 4; ++mi)
#pragma unroll
    for (int j = 0; j < 12; ++j) part[mi][j] = 0.f;

#pragma unroll
  for (int ni = 0; ni < 8; ++ni) {
    int nb = wc * 128 + ni * 16 + kl * 4;
    float4 bv4 = *reinterpret_cast<const float4*>(bias + nb);
    float bb[4] = {bv4.x, bv4.y, bv4.z, bv4.w};
#pragma unroll
    for (int rg = 0; rg < 4; ++rg) {
      const float* Pc = Pall + (size_t)(nb + rg) * 12;
      float4 p0 = *reinterpret_cast<const float4*>(Pc);
      float4 p1 = *reinterpret_cast<const float4*>(Pc + 4);
      float4 p2 = *reinterpret_cast<const float4*>(Pc + 8);
#pragma unroll
      for (int mi = 0; mi < 4; ++mi) {
        float v = acc[ni][mi][rg] + bb[rg];
        v = (v >= 0.f) ? v : NEG_SLOPE * v;
        part[mi][0] += v * p0.x; part[mi][1] += v * p0.y;
        part[mi][2] += v * p0.z; part[mi][3] += v * p0.w;
        part[mi][4] += v * p1.x; part[mi][5] += v * p1.y;
        part[mi][6] += v * p1.z; part[mi][7] += v * p1.w;
        part[mi][8] += v * p2.x; part[mi][9] += v * p2.y;
        part[mi][10] += v * p2.z; part[mi][11] += v * p2.w;
      }
    }
  }
  // reduce across kl (lanes 16/32 apart)
#pragma unroll
  for (int mi = 0; mi < 4; ++mi)
#pragma unroll
    for (int j = 0; j < 12; ++j) {
      part[mi][j] += __shfl_xor(part[mi][j], 16);
      part[mi][j] += __shfl_xor(part[mi][j], 32);
    }
  // reduce across the 4 wc-waves via LDS atomics
  if (kl == 0) {
#pragma unroll
    for (int mi = 0; mi < 4; ++mi) {
      int r = wr * 64 + mi * 16 + r15;
#pragma unroll
      for (int j = 0; j < 12; ++j) atomicAdd(&tab[r * 12 + j], part[mi][j]);
    }
  }
  __syncthreads();
  for (int i = tid; i < 1536; i += 512) {
    int r = i / 12;
    int gr = bm + r;
    if (gr < NNODES) t0[(size_t)gr * 12 + (i - r * 12)] = tab[i];
  }
}

// ---- agg pass 1 (bucketed LDS accumulate): vals = t0a[src], + degree ----
__global__ __launch_bounds__(256) void aggA(
    const unsigned int* __restrict__ pcol, const int* __restrict__ bstart,
    const float* __restrict__ t0, float* __restrict__ partial) {
  __shared__ float tab[512 * 5];
  int t = threadIdx.x;
  int b = blockIdx.x >> 3, sb = blockIdx.x & 7;
  for (int i = t; i < 2560; i += 256) tab[i] = 0.f;
  __syncthreads();
  int st = bstart[b], en = bstart[b + 1];
  int len = en - st;
  int a0 = st + (int)(((long long)len * sb) >> 3);
  int a1 = st + (int)(((long long)len * (sb + 1)) >> 3);
  for (int e = a0 + t; e < a1; e += 256) {
    unsigned v = pcol[e];
    int i = v >> 16, src = v & 0xFFFF;
    float4 x = *reinterpret_cast<const float4*>(t0 + (size_t)src * 12);
    atomicAdd(&tab[i * 5 + 0], x.x);
    atomicAdd(&tab[i * 5 + 1], x.y);
    atomicAdd(&tab[i * 5 + 2], x.z);
    atomicAdd(&tab[i * 5 + 3], x.w);
    atomicAdd(&tab[i * 5 + 4], 1.f);
  }
  __syncthreads();
  float* o = partial + (size_t)blockIdx.x * 2560;
  for (int i = t; i < 2560; i += 256) o[i] = tab[i];
}

// ---- fin pass 1: s1[n] = sum/deg + t0b[n]; store deg ----
__global__ __launch_bounds__(256) void finA(
    const float* __restrict__ partial, const float* __restrict__ t0,
    float* __restrict__ s1, float* __restrict__ degf) {
  int n = blockIdx.x * 256 + threadIdx.x;
  if (n >= NNODES) return;
  int b = n >> 9, i = n & 511;
  float a[5] = {0.f, 0.f, 0.f, 0.f, 0.f};
#pragma unroll
  for (int s = 0; s < 8; s++) {
    const float* p = partial + (size_t)(b * 8 + s) * 2560 + i * 5;
#pragma unroll
    for (int j = 0; j < 5; j++) a[j] += p[j];
  }
  float deg = a[4];
  float sc = (deg > 0.f) ? 1.f / deg : 0.f;
  float4 tb = *reinterpret_cast<const float4*>(t0 + (size_t)n * 12 + 4);
  float4 o = {a[0] * sc + tb.x, a[1] * sc + tb.y, a[2] * sc + tb.z, a[3] * sc + tb.w};
  *reinterpret_cast<float4*>(s1 + (size_t)n * 4) = o;
  degf[n] = deg;
}

// ---- agg pass 2: vals = s1[src] ----
__global__ __launch_bounds__(256) void aggB(
    const unsigned int* __restrict__ pcol, const int* __restrict__ bstart,
    const float* __restrict__ s1, float* __restrict__ partial) {
  __shared__ float tab[512 * 4];
  int t = threadIdx.x;
  int b = blockIdx.x >> 3, sb = blockIdx.x & 7;
  for (int i = t; i < 2048; i += 256) tab[i] = 0.f;
  __syncthreads();
  int st = bstart[b], en = bstart[b + 1];
  int len = en - st;
  int a0 = st + (int)(((long long)len * sb) >> 3);
  int a1 = st + (int)(((long long)len * (sb + 1)) >> 3);
  for (int e = a0 + t; e < a1; e += 256) {
    unsigned v = pcol[e];
    int i = v >> 16, src = v & 0xFFFF;
    float4 x = *reinterpret_cast<const float4*>(s1 + (size_t)src * 4);
    atomicAdd(&tab[i * 4 + 0], x.x);
    atomicAdd(&tab[i * 4 + 1], x.y);
    atomicAdd(&tab[i * 4 + 2], x.z);
    atomicAdd(&tab[i * 4 + 3], x.w);
  }
  __syncthreads();
  float* o = partial + (size_t)blockIdx.x * 2048;
  for (int i = t; i < 2048; i += 256) o[i] = tab[i];
}

// ---- fin pass 2: out[n] = sum/deg + t0c[n] + ind*kb + kc ----
__global__ __launch_bounds__(256) void finB(
    const float* __restrict__ partial, const float* __restrict__ t0,
    const float* __restrict__ degf, const float* __restrict__ kb,
    const float* __restrict__ kc, float* __restrict__ out) {
  int n = blockIdx.x * 256 + threadIdx.x;
  if (n >= NNODES) return;
  int b = n >> 9, i = n & 511;
  float a[4] = {0.f, 0.f, 0.f, 0.f};
#pragma unroll
  for (int s = 0; s < 8; s++) {
    const float* p = partial + (size_t)(b * 8 + s) * 2048 + i * 4;
#pragma unroll
    for (int j = 0; j < 4; j++) a[j] += p[j];
  }
  float deg = degf[n];
  float sc = (deg > 0.f) ? 1.f / deg : 0.f;
  float ind = (deg > 0.f) ? 1.f : 0.f;
  float4 c = *reinterpret_cast<const float4*>(t0 + (size_t)n * 12 + 8);
  float4 vb = *reinterpret_cast<const float4*>(kb);
  float4 vc = *reinterpret_cast<const float4*>(kc);
  float4 o = {a[0] * sc + c.x + ind * vb.x + vc.x,
              a[1] * sc + c.y + ind * vb.y + vc.y,
              a[2] * sc + c.z + ind * vb.z + vc.z,
              a[3] * sc + c.w + ind * vb.w + vc.w};
  *reinterpret_cast<float4*>(out + (size_t)n * 4) = o;
}

extern "C" void kernel_launch(void* const* d_in, const int* in_sizes, int n_in,
                              void* d_out, int out_size, void* d_ws, size_t ws_size,
                              hipStream_t stream) {
  const float* feat = (const float*)d_in[0];
  const int* ei = (const int*)d_in[1];
  const float* W_in = (const float*)d_in[3];
  const float* b_in = (const float*)d_in[4];
  const float* W1l = (const float*)d_in[5];
  const float* b1l = (const float*)d_in[6];
  const float* W1r = (const float*)d_in[7];
  const float* W2l = (const float*)d_in[8];
  const float* b2l = (const float*)d_in[9];
  const float* W2r = (const float*)d_in[10];
  const float* Wout = (const float*)d_in[11];
  const float* bout = (const float*)d_in[12];
  float* out = (float*)d_out;

  // ---- workspace layout, ~19 MB ----
  char* ws = (char*)d_ws;
  size_t off = 0;
  auto alloc = [&](size_t bytes) {
    void* p = ws + off;
    off += (bytes + 15) & ~(size_t)15;
    return p;
  };
  int* flag   = (int*)alloc(16);
  int* hist   = (int*)alloc((size_t)NBUCK * NBLK * 4);
  int* bstart = (int*)alloc((NBUCK + 1) * 4);
  unsigned int* pcol = (unsigned int*)alloc((size_t)NEDGES * 4);
  unsigned short* Wt0 = (unsigned short*)alloc(512 * 512 * 2);
  float* Wlp  = (float*)alloc(2048 * 4);
  float* Wrp  = (float*)alloc(2048 * 4);
  float* bp   = (float*)alloc(16);
  float* Pall = (float*)alloc(512 * 12 * 4);
  float* kb   = (float*)alloc(16);
  float* kc   = (float*)alloc(16);
  float* t0   = (float*)alloc((size_t)NNODES * 12 * 4);
  float* s1   = (float*)alloc((size_t)NNODES * 4 * 4);
  float* degf = (float*)alloc((size_t)NNODES * 4);
  float* partial = (float*)alloc((size_t)NBUCK * NSUB * 2560 * 4);
  (void)ws_size;

  // graph partition
  flagk<<<1, 64, 0, stream>>>(ei, flag);
  histk<<<NBLK, 256, 0, stream>>>(ei, flag, hist);
  scanh<<<1, 512, 0, stream>>>(hist, bstart);
  binscatter<<<NBLK, 256, 0, stream>>>(ei, flag, hist, pcol);

  // weight prep
  tcast<<<1024, 256, 0, stream>>>(W_in, Wt0);
  smallA<<<1025, 256, 0, stream>>>(W2l, W2r, Wout, b2l, bout, Wlp, Wrp, bp);
  smallB<<<1538, 256, 0, stream>>>(W1l, W1r, b1l, Wlp, Wrp, bp, Pall, kb, kc);

  // pipeline
  gemmproj<<<GPBLK, 512, 0, stream>>>(feat, Wt0, b_in, Pall, t0);
  aggA<<<NBUCK * NSUB, 256, 0, stream>>>(pcol, bstart, t0, partial);
  finA<<<(NNODES + 255) / 256, 256, 0, stream>>>(partial, t0, s1, degf);
  aggB<<<NBUCK * NSUB, 256, 0, stream>>>(pcol, bstart, s1, partial);
  finB<<<(NNODES + 255) / 256, 256, 0, stream>>>(partial, t0, degf, kb, kc, out);
}